// Round 6
// baseline (421.319 us; speedup 1.0000x reference)
//
#include <hip/hip_runtime.h>
#include <stdint.h>

// Problem constants (B,T,C,H,D) = (4,2048,1024,16,64)
#define Bb 4
#define Tt 2048
#define Cc 1024
#define Hh 16
#define Dd 64

using bf16x8 = __bf16 __attribute__((ext_vector_type(8)));
using f32x4  = float  __attribute__((ext_vector_type(4)));
typedef short s16x4 __attribute__((ext_vector_type(4)));
typedef unsigned short u16;
typedef unsigned int   u32;

// 16x16x16 bf16 MFMA (K=16)
#if defined(__has_builtin) && __has_builtin(__builtin_amdgcn_mfma_f32_16x16x16bf16_1k)
#define MFMA_16x16x16_BF16(a, b, c) __builtin_amdgcn_mfma_f32_16x16x16bf16_1k(a, b, c, 0, 0, 0)
#else
static __device__ __forceinline__ f32x4 mfma16x16x16bf16_asm(s16x4 a, s16x4 b, f32x4 c) {
  f32x4 d;
  asm volatile("v_mfma_f32_16x16x16_bf16 %0, %1, %2, %3" : "=v"(d) : "v"(a), "v"(b), "v"(c));
  return d;
}
#define MFMA_16x16x16_BF16(a, b, c) mfma16x16x16bf16_asm(a, b, c)
#endif

__device__ __forceinline__ u16 f32_to_bf16(float f) {
  union { float f; unsigned u; } v; v.f = f;
  unsigned r = v.u + 0x7fffu + ((v.u >> 16) & 1u);  // RNE
  return (u16)(r >> 16);
}
__device__ __forceinline__ short bf16rn(float f) {
  union { float f; unsigned u; } v; v.f = f;
  return (short)((v.u + 0x8000u) >> 16);
}

// async global->LDS, 16B per lane. LDS dest = wave-uniform base + lane*16.
__device__ __forceinline__ void gl2lds16(const u16* g, u16* l) {
  __builtin_amdgcn_global_load_lds(
      (const __attribute__((address_space(1))) u32*)g,
      (__attribute__((address_space(3))) u32*)l, 16, 0, 0);
}

// ---------------- casts fp32 -> bf16 ----------------
__global__ void cast_f32_to_bf16(const float* __restrict__ in, u16* __restrict__ out, int n) {
  int i = (blockIdx.x * blockDim.x + threadIdx.x) * 4;
  if (i >= n) return;
  float4 v = *reinterpret_cast<const float4*>(in + i);
  ushort4 o;
  o.x = f32_to_bf16(v.x); o.y = f32_to_bf16(v.y);
  o.z = f32_to_bf16(v.z); o.w = f32_to_bf16(v.w);
  *reinterpret_cast<ushort4*>(out + i) = o;
}

__global__ void cast4_f32_to_bf16(const float* __restrict__ w0, const float* __restrict__ w1,
                                  const float* __restrict__ w2, const float* __restrict__ w3,
                                  u16* __restrict__ o0, u16* __restrict__ o1,
                                  u16* __restrict__ o2, u16* __restrict__ o3, int n) {
  const float* in; u16* out;
  switch (blockIdx.y) {
    case 0: in = w0; out = o0; break;
    case 1: in = w1; out = o1; break;
    case 2: in = w2; out = o2; break;
    default: in = w3; out = o3; break;
  }
  int i = (blockIdx.x * blockDim.x + threadIdx.x) * 4;
  if (i >= n) return;
  float4 v = *reinterpret_cast<const float4*>(in + i);
  ushort4 o;
  o.x = f32_to_bf16(v.x); o.y = f32_to_bf16(v.y);
  o.z = f32_to_bf16(v.z); o.w = f32_to_bf16(v.w);
  *reinterpret_cast<ushort4*>(out + i) = o;
}

// ---------------- GEMM: C = (A[M,K] * B[N,K]^T + bias) * scale ----------------
// m97 recipe, BK=32 (r4-verified config).
// MODE 0: bf16 row-major [M,N]. MODE 1: fp32 row-major. MODE 2: bf16 written
// as VT [B,H,D,T] via LDS tile-transpose (fuses the old transpose_v kernel).
template<int MODE>
__global__ __launch_bounds__(256, 2)
void gemm_bt(const u16* __restrict__ A, const u16* __restrict__ Bw,
             const float* __restrict__ bias, void* __restrict__ Cout,
             int M, int N, int K, float scale)
{
  constexpr int BK = 32;
  constexpr int LDT = 136;   // epilogue transpose stride (rows of 272B, 16B-aligned)
  constexpr int SMEM_U16 = (MODE == 2) ? (128 * LDT) : (2 * 128 * BK);
  __shared__ alignas(16) u16 smem[SMEM_U16];
  u16* As = smem;
  u16* Bs = smem + 128 * BK;
  const int tid  = threadIdx.x;
  const int wave = tid >> 6, lane = tid & 63;
  const int row0 = blockIdx.x * 128, col0 = blockIdx.y * 128;
  const int wm = (wave & 1) * 64, wn = (wave >> 1) * 64;
  const int fr = lane & 15, fk = (lane >> 4) * 8;
  const int srow = lane >> 2, scol = (lane & 3) * 8;

  f32x4 acc[4][4] = {};

  for (int k0 = 0; k0 < K; k0 += BK) {
#pragma unroll
    for (int c = 0; c < 2; ++c) {
      int rg = (wave * 2 + c) * 16;
      gl2lds16(A  + (size_t)(row0 + rg + srow) * K + k0 + scol, &As[rg * BK]);
      gl2lds16(Bw + (size_t)(col0 + rg + srow) * K + k0 + scol, &Bs[rg * BK]);
    }
    __syncthreads();
    bf16x8 af[4], bf[4];
#pragma unroll
    for (int i = 0; i < 4; ++i) {
      af[i] = *reinterpret_cast<const bf16x8*>(&As[(wm + i * 16 + fr) * BK + fk]);
      bf[i] = *reinterpret_cast<const bf16x8*>(&Bs[(wn + i * 16 + fr) * BK + fk]);
    }
#pragma unroll
    for (int i = 0; i < 4; ++i)
#pragma unroll
      for (int j = 0; j < 4; ++j)
        acc[i][j] = __builtin_amdgcn_mfma_f32_16x16x32_bf16(af[i], bf[j], acc[i][j], 0, 0, 0);
    __syncthreads();
  }

  if (MODE == 2) {
    // C-tile -> smem as [col][row] bf16, then coalesced store into VT[B,H,D,T]
#pragma unroll
    for (int j = 0; j < 4; ++j) {
      int lc = wn + j * 16 + fr;
      float bv = bias[col0 + lc];
#pragma unroll
      for (int i = 0; i < 4; ++i) {
        int lr = wm + i * 16 + (lane >> 4) * 4;
#pragma unroll
        for (int r = 0; r < 4; ++r)
          smem[lc * LDT + lr + r] = f32_to_bf16((acc[i][j][r] + bv) * scale);
      }
    }
    __syncthreads();
    int lc = tid >> 1, seg = tid & 1;
    int col = col0 + lc;                 // = h*64 + d
    int h = col >> 6, d = col & 63;
    int bb = row0 >> 11, t0 = (row0 & 2047) + seg * 64;
    u16* dst = (u16*)Cout + ((size_t)(bb * Hh + h) * Dd + d) * Tt + t0;
    const u16* src = &smem[lc * LDT + seg * 64];
#pragma unroll
    for (int g = 0; g < 8; ++g)
      *reinterpret_cast<uint4*>(dst + g * 8) = *reinterpret_cast<const uint4*>(src + g * 8);
  } else {
#pragma unroll
    for (int j = 0; j < 4; ++j) {
      int col = col0 + wn + j * 16 + fr;
      float bv = bias[col];
#pragma unroll
      for (int i = 0; i < 4; ++i) {
        int rowb = row0 + wm + i * 16 + (lane >> 4) * 4;
#pragma unroll
        for (int r = 0; r < 4; ++r) {
          float v = (acc[i][j][r] + bv) * scale;
          size_t idx = (size_t)(rowb + r) * N + col;
          if (MODE == 0) reinterpret_cast<u16*>(Cout)[idx] = f32_to_bf16(v);
          else           reinterpret_cast<float*>(Cout)[idx] = v;
        }
      }
    }
  }
}

// ---------------- attention: barrier-free K-loop, wave-owns-keys ----------------
// grid (B*H, T/64): x=bh so all qt-blocks of one bh land on one XCD (id%8 const).
// Wave w owns keys [kt+16w,+16) for ALL 64 q of the block. K and V^T fragments
// load directly global->registers (L2-served); no LDS, no barriers in the loop.
// S^T C-layout feeds PV B-operand in-register. Unnormalized softmax (scores
// bounded; Q pre-scaled by (1/sqrt(D))*log2e). Epilogue reduces the 4 waves'
// partial O^T and per-q sums through LDS once.
__global__ __launch_bounds__(256, 2)
void attn_kernel(const u16* __restrict__ Q, const u16* __restrict__ Kmat,
                 const u16* __restrict__ VT, u16* __restrict__ O) {
  __shared__ alignas(16) float Of[64 * 68];   // O^T reduced: [q][d] (68 pad)
  __shared__ float Qs[4 * 64];                // per-wave q-sums
  const int tid = threadIdx.x, wave = tid >> 6, lane = tid & 63;
  const int bh = blockIdx.x, qt = blockIdx.y;
  const int b = bh >> 4, h = bh & 15;
  const size_t base = (size_t)b * Tt * Cc + (size_t)h * Dd;
  const int fr = lane & 15, qd = lane >> 4;

  // Q fragments for all 4 q-blocks (B-operand: B[k=qd*8+j][n=fr])
  bf16x8 bq0[4], bq1[4];
#pragma unroll
  for (int nb = 0; nb < 4; ++nb) {
    const u16* qp = Q + base + (size_t)(qt * 64 + nb * 16 + fr) * Cc + qd * 8;
    bq0[nb] = *reinterpret_cast<const bf16x8*>(qp);
    bq1[nb] = *reinterpret_cast<const bf16x8*>(qp + 32);
  }

  f32x4 Oacc[4][4] = {};     // [n=dblock][nb=qblock]; O^T[d=n*16+qd*4+r][q=nb*16+fr]
  float sacc[4] = {0.f, 0.f, 0.f, 0.f};
  const size_t vtb = (size_t)bh * Dd * Tt;

  const u16* kp = Kmat + base + (size_t)(wave * 16 + fr) * Cc + qd * 8;
  const u16* vp = VT + vtb + (size_t)fr * Tt + wave * 16 + qd * 4;

  // preload first fragments
  bf16x8 ka = *reinterpret_cast<const bf16x8*>(kp);
  bf16x8 kb = *reinterpret_cast<const bf16x8*>(kp + 32);
  s16x4 va[4];
#pragma unroll
  for (int n = 0; n < 4; ++n)
    va[n] = *reinterpret_cast<const s16x4*>(vp + (size_t)n * 16 * Tt);

  for (int kt = 0; kt < Tt; kt += 64) {
    // prefetch next iteration (clamped so the tail re-reads in-bounds)
    const int adv = (kt + 64 < Tt) ? 64 : 0;
    const u16* kpn = kp + (size_t)adv * Cc;
    const u16* vpn = vp + adv;
    bf16x8 nka = *reinterpret_cast<const bf16x8*>(kpn);
    bf16x8 nkb = *reinterpret_cast<const bf16x8*>(kpn + 32);
    s16x4 nva[4];
#pragma unroll
    for (int n = 0; n < 4; ++n)
      nva[n] = *reinterpret_cast<const s16x4*>(vpn + (size_t)n * 16 * Tt);

    // S^T for this wave's 16 keys x all 64 q; exp2; pack
    s16x4 pf[4];
#pragma unroll
    for (int nb = 0; nb < 4; ++nb) {
      f32x4 z = {};
      z = __builtin_amdgcn_mfma_f32_16x16x32_bf16(ka, bq0[nb], z, 0, 0, 0);
      f32x4 st = __builtin_amdgcn_mfma_f32_16x16x32_bf16(kb, bq1[nb], z, 0, 0, 0);
      float p0 = exp2f(st[0]), p1 = exp2f(st[1]);
      float p2 = exp2f(st[2]), p3 = exp2f(st[3]);
      sacc[nb] += (p0 + p1) + (p2 + p3);
      s16x4 pv; pv[0] = bf16rn(p0); pv[1] = bf16rn(p1);
      pv[2] = bf16rn(p2); pv[3] = bf16rn(p3);
      pf[nb] = pv;
    }

    // O^T += V^T * P^T (A: m=d, k=key; B: k=key, n=q)
#pragma unroll
    for (int n = 0; n < 4; ++n)
#pragma unroll
      for (int nb = 0; nb < 4; ++nb)
        Oacc[n][nb] = MFMA_16x16x16_BF16(va[n], pf[nb], Oacc[n][nb]);

    ka = nka; kb = nkb;
#pragma unroll
    for (int n = 0; n < 4; ++n) va[n] = nva[n];
    kp = kpn; vp = vpn;
  }

  // ---- epilogue: reduce q-sums and partial O^T across the 4 waves ----
#pragma unroll
  for (int nb = 0; nb < 4; ++nb) {
    float s = sacc[nb];
    s += __shfl_xor(s, 16, 64);
    s += __shfl_xor(s, 32, 64);
    if (qd == 0) Qs[wave * 64 + nb * 16 + fr] = s;
  }
  for (int w = 0; w < 4; ++w) {
    if (wave == w) {
#pragma unroll
      for (int n = 0; n < 4; ++n)
#pragma unroll
        for (int nb = 0; nb < 4; ++nb) {
          float* dst = &Of[(nb * 16 + fr) * 68 + n * 16 + qd * 4];
          if (w == 0) *reinterpret_cast<f32x4*>(dst) = Oacc[n][nb];
          else {
            f32x4 old = *reinterpret_cast<const f32x4*>(dst);
            *reinterpret_cast<f32x4*>(dst) = old + Oacc[n][nb];
          }
        }
    }
    __syncthreads();
  }

  // normalize + store: thread handles q = tid>>2, d-range (tid&3)*16..+15
  {
    int q = tid >> 2, dg = tid & 3;
    float qtot = Qs[q] + Qs[64 + q] + Qs[128 + q] + Qs[192 + q];
    float linv = 1.0f / qtot;
    const float* src = &Of[q * 68 + dg * 16];
    alignas(16) u16 tmp[16];
#pragma unroll
    for (int i = 0; i < 16; ++i) tmp[i] = f32_to_bf16(src[i] * linv);
    u16* op = O + base + (size_t)(qt * 64 + q) * Cc + dg * 16;
    *reinterpret_cast<uint4*>(op)     = *reinterpret_cast<const uint4*>(tmp);
    *reinterpret_cast<uint4*>(op + 8) = *reinterpret_cast<const uint4*>(tmp + 8);
  }
}

extern "C" void kernel_launch(void* const* d_in, const int* in_sizes, int n_in,
                              void* d_out, int out_size, void* d_ws, size_t ws_size,
                              hipStream_t stream) {
  const float* x  = (const float*)d_in[0];
  const float* Wq = (const float*)d_in[1];
  const float* bq = (const float*)d_in[2];
  const float* Wk = (const float*)d_in[3];
  const float* bk = (const float*)d_in[4];
  const float* Wv = (const float*)d_in[5];
  const float* bv = (const float*)d_in[6];
  const float* Wo = (const float*)d_in[7];
  const float* bo = (const float*)d_in[8];

  const size_t NX = (size_t)Bb * Tt * Cc;  // 8388608
  const size_t NW = (size_t)Cc * Cc;       // 1048576

  u16* ws  = (u16*)d_ws;
  u16* xb  = ws;
  u16* wqb = ws + NX;
  u16* wkb = wqb + NW;
  u16* wvb = wkb + NW;
  u16* wob = wvb + NW;
  u16* qb  = wob + NW;
  u16* kb  = qb + NX;
  u16* vtb = kb + NX;
  u16* attnb = xb;  // alias: x dead once projections are done

  cast_f32_to_bf16<<<(int)(NX / 4 / 256), 256, 0, stream>>>(x, xb, (int)NX);
  cast4_f32_to_bf16<<<dim3((unsigned)(NW / 4 / 256), 4), 256, 0, stream>>>(
      Wq, Wk, Wv, Wo, wqb, wkb, wvb, wob, (int)NW);

  dim3 gg(64, 8);
  const float QSCL = 0.125f * 1.44269504f;  // 1/sqrt(D) * log2(e), folded into Q
  gemm_bt<0><<<gg, 256, 0, stream>>>(xb, wqb, bq, qb, Bb * Tt, Cc, Cc, QSCL);
  gemm_bt<0><<<gg, 256, 0, stream>>>(xb, wkb, bk, kb, Bb * Tt, Cc, Cc, 1.0f);
  gemm_bt<2><<<gg, 256, 0, stream>>>(xb, wvb, bv, vtb, Bb * Tt, Cc, Cc, 1.0f);

  attn_kernel<<<dim3(Bb * Hh, Tt / 64), 256, 0, stream>>>(qb, kb, vtb, attnb);

  gemm_bt<1><<<gg, 256, 0, stream>>>(attnb, wob, bo, d_out, Bb * Tt, Cc, Cc, 1.0f);
}

// Round 7
// 334.910 us; speedup vs baseline: 1.2580x; 1.2580x over previous
//
#include <hip/hip_runtime.h>
#include <stdint.h>

// Problem constants (B,T,C,H,D) = (4,2048,1024,16,64)
#define Bb 4
#define Tt 2048
#define Cc 1024
#define Hh 16
#define Dd 64

using bf16x8 = __bf16 __attribute__((ext_vector_type(8)));
using f32x4  = float  __attribute__((ext_vector_type(4)));
typedef short s16x4 __attribute__((ext_vector_type(4)));
typedef unsigned short u16;
typedef unsigned int   u32;

// 16x16x16 bf16 MFMA (K=16)
#if defined(__has_builtin) && __has_builtin(__builtin_amdgcn_mfma_f32_16x16x16bf16_1k)
#define MFMA_16x16x16_BF16(a, b, c) __builtin_amdgcn_mfma_f32_16x16x16bf16_1k(a, b, c, 0, 0, 0)
#else
static __device__ __forceinline__ f32x4 mfma16x16x16bf16_asm(s16x4 a, s16x4 b, f32x4 c) {
  f32x4 d;
  asm volatile("v_mfma_f32_16x16x16_bf16 %0, %1, %2, %3" : "=v"(d) : "v"(a), "v"(b), "v"(c));
  return d;
}
#define MFMA_16x16x16_BF16(a, b, c) mfma16x16x16bf16_asm(a, b, c)
#endif

__device__ __forceinline__ u16 f32_to_bf16(float f) {
  union { float f; unsigned u; } v; v.f = f;
  unsigned r = v.u + 0x7fffu + ((v.u >> 16) & 1u);  // RNE
  return (u16)(r >> 16);
}
__device__ __forceinline__ short bf16rn(float f) {
  union { float f; unsigned u; } v; v.f = f;
  return (short)((v.u + 0x8000u) >> 16);
}

// async global->LDS, 16B per lane. LDS dest = wave-uniform base + lane*16.
__device__ __forceinline__ void gl2lds16(const u16* g, u16* l) {
  __builtin_amdgcn_global_load_lds(
      (const __attribute__((address_space(1))) u32*)g,
      (__attribute__((address_space(3))) u32*)l, 16, 0, 0);
}

// ---------------- casts fp32 -> bf16 ----------------
__global__ void cast_f32_to_bf16(const float* __restrict__ in, u16* __restrict__ out, int n) {
  int i = (blockIdx.x * blockDim.x + threadIdx.x) * 4;
  if (i >= n) return;
  float4 v = *reinterpret_cast<const float4*>(in + i);
  ushort4 o;
  o.x = f32_to_bf16(v.x); o.y = f32_to_bf16(v.y);
  o.z = f32_to_bf16(v.z); o.w = f32_to_bf16(v.w);
  *reinterpret_cast<ushort4*>(out + i) = o;
}

__global__ void cast4_f32_to_bf16(const float* __restrict__ w0, const float* __restrict__ w1,
                                  const float* __restrict__ w2, const float* __restrict__ w3,
                                  u16* __restrict__ o0, u16* __restrict__ o1,
                                  u16* __restrict__ o2, u16* __restrict__ o3, int n) {
  const float* in; u16* out;
  switch (blockIdx.y) {
    case 0: in = w0; out = o0; break;
    case 1: in = w1; out = o1; break;
    case 2: in = w2; out = o2; break;
    default: in = w3; out = o3; break;
  }
  int i = (blockIdx.x * blockDim.x + threadIdx.x) * 4;
  if (i >= n) return;
  float4 v = *reinterpret_cast<const float4*>(in + i);
  ushort4 o;
  o.x = f32_to_bf16(v.x); o.y = f32_to_bf16(v.y);
  o.z = f32_to_bf16(v.z); o.w = f32_to_bf16(v.w);
  *reinterpret_cast<ushort4*>(out + i) = o;
}

// ---------------- GEMM: C = (A[M,K] * B[N,K]^T + bias) * scale ----------------
// m97 recipe, BK=32. MODE 0: bf16 [M,N]. MODE 1: fp32 [M,N].
// MODE 2: bf16 written as VT [B,H,D,T] via LDS tile-transpose.
template<int MODE>
__global__ __launch_bounds__(256, 2)
void gemm_bt(const u16* __restrict__ A, const u16* __restrict__ Bw,
             const float* __restrict__ bias, void* __restrict__ Cout,
             int M, int N, int K, float scale)
{
  constexpr int BK = 32;
  constexpr int LDT = 136;
  constexpr int SMEM_U16 = (MODE == 2) ? (128 * LDT) : (2 * 128 * BK);
  __shared__ alignas(16) u16 smem[SMEM_U16];
  u16* As = smem;
  u16* Bs = smem + 128 * BK;
  const int tid  = threadIdx.x;
  const int wave = tid >> 6, lane = tid & 63;
  const int row0 = blockIdx.x * 128, col0 = blockIdx.y * 128;
  const int wm = (wave & 1) * 64, wn = (wave >> 1) * 64;
  const int fr = lane & 15, fk = (lane >> 4) * 8;
  const int srow = lane >> 2, scol = (lane & 3) * 8;

  f32x4 acc[4][4] = {};

  for (int k0 = 0; k0 < K; k0 += BK) {
#pragma unroll
    for (int c = 0; c < 2; ++c) {
      int rg = (wave * 2 + c) * 16;
      gl2lds16(A  + (size_t)(row0 + rg + srow) * K + k0 + scol, &As[rg * BK]);
      gl2lds16(Bw + (size_t)(col0 + rg + srow) * K + k0 + scol, &Bs[rg * BK]);
    }
    __syncthreads();
    bf16x8 af[4], bf[4];
#pragma unroll
    for (int i = 0; i < 4; ++i) {
      af[i] = *reinterpret_cast<const bf16x8*>(&As[(wm + i * 16 + fr) * BK + fk]);
      bf[i] = *reinterpret_cast<const bf16x8*>(&Bs[(wn + i * 16 + fr) * BK + fk]);
    }
#pragma unroll
    for (int i = 0; i < 4; ++i)
#pragma unroll
      for (int j = 0; j < 4; ++j)
        acc[i][j] = __builtin_amdgcn_mfma_f32_16x16x32_bf16(af[i], bf[j], acc[i][j], 0, 0, 0);
    __syncthreads();
  }

  if (MODE == 2) {
#pragma unroll
    for (int j = 0; j < 4; ++j) {
      int lc = wn + j * 16 + fr;
      float bv = bias[col0 + lc];
#pragma unroll
      for (int i = 0; i < 4; ++i) {
        int lr = wm + i * 16 + (lane >> 4) * 4;
#pragma unroll
        for (int r = 0; r < 4; ++r)
          smem[lc * LDT + lr + r] = f32_to_bf16((acc[i][j][r] + bv) * scale);
      }
    }
    __syncthreads();
    int lc = tid >> 1, seg = tid & 1;
    int col = col0 + lc;                 // = h*64 + d
    int h = col >> 6, d = col & 63;
    int bb = row0 >> 11, t0 = (row0 & 2047) + seg * 64;
    u16* dst = (u16*)Cout + ((size_t)(bb * Hh + h) * Dd + d) * Tt + t0;
    const u16* src = &smem[lc * LDT + seg * 64];
#pragma unroll
    for (int g = 0; g < 8; ++g)
      *reinterpret_cast<uint4*>(dst + g * 8) = *reinterpret_cast<const uint4*>(src + g * 8);
  } else {
#pragma unroll
    for (int j = 0; j < 4; ++j) {
      int col = col0 + wn + j * 16 + fr;
      float bv = bias[col];
#pragma unroll
      for (int i = 0; i < 4; ++i) {
        int rowb = row0 + wm + i * 16 + (lane >> 4) * 4;
#pragma unroll
        for (int r = 0; r < 4; ++r) {
          float v = (acc[i][j][r] + bv) * scale;
          size_t idx = (size_t)(rowb + r) * N + col;
          if (MODE == 0) reinterpret_cast<u16*>(Cout)[idx] = f32_to_bf16(v);
          else           reinterpret_cast<float*>(Cout)[idx] = v;
        }
      }
    }
  }
}

// ---------------- attention: LDS-staged tiles + wave-owns-keys ----------------
// grid (B*H, T/64). LDS staging hides global latency (r4-verified); wave w
// computes only its 16-key stripe -> LDS reads are 4 KB/wave/tile instead of
// 16 KB (the r4/r5 LDS-BW wall, cut 3x). P^T stays in registers (C-layout of
// K=32 MFMA == B-operand of K=16 MFMA). Unnormalized softmax (scores bounded;
// Q pre-scaled by (1/sqrt(D))*log2e). r6-verified cross-wave epilogue.
__global__ __launch_bounds__(256, 2)
void attn_kernel(const u16* __restrict__ Q, const u16* __restrict__ Kmat,
                 const u16* __restrict__ VT, u16* __restrict__ O) {
  constexpr int LDK = 72, LDV = 72;
  // union: loop phase Ks(9216)+Vs(9216) == epilogue Of(17408)+Qs(1024)
  __shared__ alignas(16) unsigned char smem[18432];
  u16* Ks = (u16*)smem;                       // [key][d]
  u16* Vs = (u16*)(smem + 9216);              // [d][key]
  float* Of = (float*)smem;                   // [q][68]
  float* Qs = (float*)(smem + 17408);         // [wave][64]
  const int tid = threadIdx.x, wave = tid >> 6, lane = tid & 63;
  const int bh = blockIdx.x, qt = blockIdx.y;
  const int b = bh >> 4, h = bh & 15;
  const size_t base = (size_t)b * Tt * Cc + (size_t)h * Dd;
  const int fr = lane & 15, qd = lane >> 4;

  // Q fragments for all 4 q-blocks (B-operand: B[k=qd*8+j][n=fr])
  bf16x8 bq0[4], bq1[4];
#pragma unroll
  for (int nb = 0; nb < 4; ++nb) {
    const u16* qp = Q + base + (size_t)(qt * 64 + nb * 16 + fr) * Cc + qd * 8;
    bq0[nb] = *reinterpret_cast<const bf16x8*>(qp);
    bq1[nb] = *reinterpret_cast<const bf16x8*>(qp + 32);
  }

  f32x4 Oacc[4][4] = {};     // [n=dblock][nb=qblock]; O^T[d=n*16+qd*4+r][q=nb*16+fr]
  float sacc[4] = {0.f, 0.f, 0.f, 0.f};
  const size_t vtb = (size_t)bh * Dd * Tt;
  const int sr = tid >> 3, sc = (tid & 7) * 8;   // staging: 2 iters of 32 rows

  for (int kt = 0; kt < Tt; kt += 64) {
    // stage K tile [64 keys][64 d] and V^T tile [64 d][64 keys]
#pragma unroll
    for (int it = 0; it < 2; ++it) {
      int r = it * 32 + sr;
      *reinterpret_cast<uint4*>(&Ks[r * LDK + sc]) =
          *reinterpret_cast<const uint4*>(Kmat + base + (size_t)(kt + r) * Cc + sc);
      *reinterpret_cast<uint4*>(&Vs[r * LDV + sc]) =
          *reinterpret_cast<const uint4*>(VT + vtb + (size_t)r * Tt + kt + sc);
    }
    __syncthreads();

    // this wave's 16-key stripe
    bf16x8 ka = *reinterpret_cast<const bf16x8*>(&Ks[(wave * 16 + fr) * LDK + qd * 8]);
    bf16x8 kb = *reinterpret_cast<const bf16x8*>(&Ks[(wave * 16 + fr) * LDK + 32 + qd * 8]);
    s16x4 va[4];
#pragma unroll
    for (int n = 0; n < 4; ++n)
      va[n] = *reinterpret_cast<const s16x4*>(&Vs[(n * 16 + fr) * LDV + wave * 16 + qd * 4]);

    // S^T (16 keys x 64 q), exp2, pack
    s16x4 pf[4];
#pragma unroll
    for (int nb = 0; nb < 4; ++nb) {
      f32x4 z = {};
      z = __builtin_amdgcn_mfma_f32_16x16x32_bf16(ka, bq0[nb], z, 0, 0, 0);
      f32x4 st = __builtin_amdgcn_mfma_f32_16x16x32_bf16(kb, bq1[nb], z, 0, 0, 0);
      float p0 = exp2f(st[0]), p1 = exp2f(st[1]);
      float p2 = exp2f(st[2]), p3 = exp2f(st[3]);
      sacc[nb] += (p0 + p1) + (p2 + p3);
      s16x4 pv; pv[0] = bf16rn(p0); pv[1] = bf16rn(p1);
      pv[2] = bf16rn(p2); pv[3] = bf16rn(p3);
      pf[nb] = pv;
    }

    // O^T += V^T * P^T (A: m=d, k=key; B: k=key, n=q)
#pragma unroll
    for (int n = 0; n < 4; ++n)
#pragma unroll
      for (int nb = 0; nb < 4; ++nb)
        Oacc[n][nb] = MFMA_16x16x16_BF16(va[n], pf[nb], Oacc[n][nb]);

    __syncthreads();
  }

  // ---- epilogue: reduce q-sums and partial O^T across the 4 waves ----
#pragma unroll
  for (int nb = 0; nb < 4; ++nb) {
    float s = sacc[nb];
    s += __shfl_xor(s, 16, 64);
    s += __shfl_xor(s, 32, 64);
    if (qd == 0) Qs[wave * 64 + nb * 16 + fr] = s;
  }
  for (int w = 0; w < 4; ++w) {
    if (wave == w) {
#pragma unroll
      for (int n = 0; n < 4; ++n)
#pragma unroll
        for (int nb = 0; nb < 4; ++nb) {
          float* dst = &Of[(nb * 16 + fr) * 68 + n * 16 + qd * 4];
          if (w == 0) *reinterpret_cast<f32x4*>(dst) = Oacc[n][nb];
          else {
            f32x4 old = *reinterpret_cast<const f32x4*>(dst);
            *reinterpret_cast<f32x4*>(dst) = old + Oacc[n][nb];
          }
        }
    }
    __syncthreads();
  }

  // normalize + store: thread handles q = tid>>2, d-range (tid&3)*16..+15
  {
    int q = tid >> 2, dg = tid & 3;
    float qtot = Qs[q] + Qs[64 + q] + Qs[128 + q] + Qs[192 + q];
    float linv = 1.0f / qtot;
    const float* src = &Of[q * 68 + dg * 16];
    alignas(16) u16 tmp[16];
#pragma unroll
    for (int i = 0; i < 16; ++i) tmp[i] = f32_to_bf16(src[i] * linv);
    u16* op = O + base + (size_t)(qt * 64 + q) * Cc + dg * 16;
    *reinterpret_cast<uint4*>(op)     = *reinterpret_cast<const uint4*>(tmp);
    *reinterpret_cast<uint4*>(op + 8) = *reinterpret_cast<const uint4*>(tmp + 8);
  }
}

extern "C" void kernel_launch(void* const* d_in, const int* in_sizes, int n_in,
                              void* d_out, int out_size, void* d_ws, size_t ws_size,
                              hipStream_t stream) {
  const float* x  = (const float*)d_in[0];
  const float* Wq = (const float*)d_in[1];
  const float* bq = (const float*)d_in[2];
  const float* Wk = (const float*)d_in[3];
  const float* bk = (const float*)d_in[4];
  const float* Wv = (const float*)d_in[5];
  const float* bv = (const float*)d_in[6];
  const float* Wo = (const float*)d_in[7];
  const float* bo = (const float*)d_in[8];

  const size_t NX = (size_t)Bb * Tt * Cc;  // 8388608
  const size_t NW = (size_t)Cc * Cc;       // 1048576

  u16* ws  = (u16*)d_ws;
  u16* xb  = ws;
  u16* wqb = ws + NX;
  u16* wkb = wqb + NW;
  u16* wvb = wkb + NW;
  u16* wob = wvb + NW;
  u16* qb  = wob + NW;
  u16* kb  = qb + NX;
  u16* vtb = kb + NX;
  u16* attnb = xb;  // alias: x dead once projections are done

  cast_f32_to_bf16<<<(int)(NX / 4 / 256), 256, 0, stream>>>(x, xb, (int)NX);
  cast4_f32_to_bf16<<<dim3((unsigned)(NW / 4 / 256), 4), 256, 0, stream>>>(
      Wq, Wk, Wv, Wo, wqb, wkb, wvb, wob, (int)NW);

  dim3 gg(64, 8);
  const float QSCL = 0.125f * 1.44269504f;  // 1/sqrt(D) * log2(e), folded into Q
  gemm_bt<0><<<gg, 256, 0, stream>>>(xb, wqb, bq, qb, Bb * Tt, Cc, Cc, QSCL);
  gemm_bt<0><<<gg, 256, 0, stream>>>(xb, wkb, bk, kb, Bb * Tt, Cc, Cc, 1.0f);
  gemm_bt<2><<<gg, 256, 0, stream>>>(xb, wvb, bv, vtb, Bb * Tt, Cc, Cc, 1.0f);

  attn_kernel<<<dim3(Bb * Hh, Tt / 64), 256, 0, stream>>>(qb, kb, vtb, attnb);

  gemm_bt<1><<<gg, 256, 0, stream>>>(attnb, wob, bo, d_out, Bb * Tt, Cc, Cc, 1.0f);
}

// Round 8
// 310.478 us; speedup vs baseline: 1.3570x; 1.0787x over previous
//
#include <hip/hip_runtime.h>
#include <hip/hip_bf16.h>
#include <stdint.h>

// Problem constants (B,T,C,H,D) = (4,2048,1024,16,64)
#define Bb 4
#define Tt 2048
#define Cc 1024
#define Hh 16
#define Dd 64

using bf16x8 = __bf16 __attribute__((ext_vector_type(8)));
using f32x4  = float  __attribute__((ext_vector_type(4)));
using f32x2  = float  __attribute__((ext_vector_type(2)));
typedef short s16x4 __attribute__((ext_vector_type(4)));
typedef unsigned short u16;
typedef unsigned int   u32;

// 16x16x16 bf16 MFMA (K=16)
#if defined(__has_builtin) && __has_builtin(__builtin_amdgcn_mfma_f32_16x16x16bf16_1k)
#define MFMA_16x16x16_BF16(a, b, c) __builtin_amdgcn_mfma_f32_16x16x16bf16_1k(a, b, c, 0, 0, 0)
#else
static __device__ __forceinline__ f32x4 mfma16x16x16bf16_asm(s16x4 a, s16x4 b, f32x4 c) {
  f32x4 d;
  asm volatile("v_mfma_f32_16x16x16_bf16 %0, %1, %2, %3" : "=v"(d) : "v"(a), "v"(b), "v"(c));
  return d;
}
#define MFMA_16x16x16_BF16(a, b, c) mfma16x16x16bf16_asm(a, b, c)
#endif

#if defined(__has_builtin) && __has_builtin(__builtin_amdgcn_exp2f)
#define EXP2F(x) __builtin_amdgcn_exp2f(x)
#else
#define EXP2F(x) exp2f(x)
#endif

__device__ __forceinline__ u16 f32_to_bf16(float f) {
  union { float f; unsigned u; } v; v.f = f;
  unsigned r = v.u + 0x7fffu + ((v.u >> 16) & 1u);  // RNE
  return (u16)(r >> 16);
}

// async global->LDS, 16B per lane. LDS dest = wave-uniform base + lane*16.
__device__ __forceinline__ void gl2lds16(const u16* g, u16* l) {
  __builtin_amdgcn_global_load_lds(
      (const __attribute__((address_space(1))) u32*)g,
      (__attribute__((address_space(3))) u32*)l, 16, 0, 0);
}

// ---------------- casts fp32 -> bf16 ----------------
__global__ void cast_f32_to_bf16(const float* __restrict__ in, u16* __restrict__ out, int n) {
  int i = (blockIdx.x * blockDim.x + threadIdx.x) * 4;
  if (i >= n) return;
  float4 v = *reinterpret_cast<const float4*>(in + i);
  ushort4 o;
  o.x = f32_to_bf16(v.x); o.y = f32_to_bf16(v.y);
  o.z = f32_to_bf16(v.z); o.w = f32_to_bf16(v.w);
  *reinterpret_cast<ushort4*>(out + i) = o;
}

__global__ void cast4_f32_to_bf16(const float* __restrict__ w0, const float* __restrict__ w1,
                                  const float* __restrict__ w2, const float* __restrict__ w3,
                                  u16* __restrict__ o0, u16* __restrict__ o1,
                                  u16* __restrict__ o2, u16* __restrict__ o3, int n) {
  const float* in; u16* out;
  switch (blockIdx.y) {
    case 0: in = w0; out = o0; break;
    case 1: in = w1; out = o1; break;
    case 2: in = w2; out = o2; break;
    default: in = w3; out = o3; break;
  }
  int i = (blockIdx.x * blockDim.x + threadIdx.x) * 4;
  if (i >= n) return;
  float4 v = *reinterpret_cast<const float4*>(in + i);
  ushort4 o;
  o.x = f32_to_bf16(v.x); o.y = f32_to_bf16(v.y);
  o.z = f32_to_bf16(v.z); o.w = f32_to_bf16(v.w);
  *reinterpret_cast<ushort4*>(out + i) = o;
}

// ---------------- fused QKV projection GEMM ----------------
// A[8192,1024] bf16, Bqkv[3072,1024] bf16 (Wq|Wk|Wv rows). grid (64, 24):
// by 0-7 -> Q (scale QSCL -> qout), 8-15 -> K (-> kout),
// 16-23 -> V (LDS tile-transpose -> VT[B,H,D,T]).
__global__ __launch_bounds__(256, 2)
void gemm_qkv(const u16* __restrict__ A, const u16* __restrict__ Bqkv,
              const float* __restrict__ bq, const float* __restrict__ bk,
              const float* __restrict__ bv,
              u16* __restrict__ qout, u16* __restrict__ kout, u16* __restrict__ vtout,
              float qscl)
{
  constexpr int K = Cc, BK = 32, LDT = 136;
  __shared__ alignas(16) u16 smem[128 * LDT];   // >= 2*128*BK; reused for transpose
  u16* As = smem;
  u16* Bs = smem + 128 * BK;
  const int tid  = threadIdx.x;
  const int wave = tid >> 6, lane = tid & 63;
  const int row0 = blockIdx.x * 128, col0 = blockIdx.y * 128;   // col0 in [0,3072)
  const int seg  = col0 >> 10;                                   // 0=q 1=k 2=v
  const int wm = (wave & 1) * 64, wn = (wave >> 1) * 64;
  const int fr = lane & 15, fk = (lane >> 4) * 8;
  const int srow = lane >> 2, scol = (lane & 3) * 8;

  f32x4 acc[4][4] = {};

  for (int k0 = 0; k0 < K; k0 += BK) {
#pragma unroll
    for (int c = 0; c < 2; ++c) {
      int rg = (wave * 2 + c) * 16;
      gl2lds16(A    + (size_t)(row0 + rg + srow) * K + k0 + scol, &As[rg * BK]);
      gl2lds16(Bqkv + (size_t)(col0 + rg + srow) * K + k0 + scol, &Bs[rg * BK]);
    }
    __syncthreads();
    bf16x8 af[4], bf[4];
#pragma unroll
    for (int i = 0; i < 4; ++i) {
      af[i] = *reinterpret_cast<const bf16x8*>(&As[(wm + i * 16 + fr) * BK + fk]);
      bf[i] = *reinterpret_cast<const bf16x8*>(&Bs[(wn + i * 16 + fr) * BK + fk]);
    }
#pragma unroll
    for (int i = 0; i < 4; ++i)
#pragma unroll
      for (int j = 0; j < 4; ++j)
        acc[i][j] = __builtin_amdgcn_mfma_f32_16x16x32_bf16(af[i], bf[j], acc[i][j], 0, 0, 0);
    __syncthreads();
  }

  const float* bias = (seg == 0) ? bq : ((seg == 1) ? bk : bv);
  const float scale = (seg == 0) ? qscl : 1.0f;
  const int colL0 = col0 & 1023;   // local column base within the segment

  if (seg < 2) {
    u16* outp = (seg == 0) ? qout : kout;
#pragma unroll
    for (int j = 0; j < 4; ++j) {
      int col = colL0 + wn + j * 16 + fr;
      float bvv = bias[col];
#pragma unroll
      for (int i = 0; i < 4; ++i) {
        int rowb = row0 + wm + i * 16 + (lane >> 4) * 4;
#pragma unroll
        for (int r = 0; r < 4; ++r)
          outp[(size_t)(rowb + r) * Cc + col] = f32_to_bf16((acc[i][j][r] + bvv) * scale);
      }
    }
  } else {
    // V: C-tile -> smem [col][row] bf16 -> coalesced store into VT[B,H,D,T]
#pragma unroll
    for (int j = 0; j < 4; ++j) {
      int lc = wn + j * 16 + fr;
      float bvv = bias[colL0 + lc];
#pragma unroll
      for (int i = 0; i < 4; ++i) {
        int lr = wm + i * 16 + (lane >> 4) * 4;
#pragma unroll
        for (int r = 0; r < 4; ++r)
          smem[lc * LDT + lr + r] = f32_to_bf16(acc[i][j][r] + bvv);
      }
    }
    __syncthreads();
    int lc = tid >> 1, seg2 = tid & 1;
    int col = colL0 + lc;                 // = h*64 + d
    int h = col >> 6, d = col & 63;
    int bb = row0 >> 11, t0 = (row0 & 2047) + seg2 * 64;
    u16* dst = vtout + ((size_t)(bb * Hh + h) * Dd + d) * Tt + t0;
    const u16* src = &smem[lc * LDT + seg2 * 64];
#pragma unroll
    for (int g = 0; g < 8; ++g)
      *reinterpret_cast<uint4*>(dst + g * 8) = *reinterpret_cast<const uint4*>(src + g * 8);
  }
}

// ---------------- output GEMM: C fp32 = A[M,K]*B[N,K]^T + bias ----------------
__global__ __launch_bounds__(256, 2)
void gemm_out(const u16* __restrict__ A, const u16* __restrict__ Bw,
              const float* __restrict__ bias, float* __restrict__ Cout,
              int M, int N, int K)
{
  constexpr int BK = 32;
  __shared__ alignas(16) u16 As[128 * BK];
  __shared__ alignas(16) u16 Bs[128 * BK];
  const int tid  = threadIdx.x;
  const int wave = tid >> 6, lane = tid & 63;
  const int row0 = blockIdx.x * 128, col0 = blockIdx.y * 128;
  const int wm = (wave & 1) * 64, wn = (wave >> 1) * 64;
  const int fr = lane & 15, fk = (lane >> 4) * 8;
  const int srow = lane >> 2, scol = (lane & 3) * 8;

  f32x4 acc[4][4] = {};

  for (int k0 = 0; k0 < K; k0 += BK) {
#pragma unroll
    for (int c = 0; c < 2; ++c) {
      int rg = (wave * 2 + c) * 16;
      gl2lds16(A  + (size_t)(row0 + rg + srow) * K + k0 + scol, &As[rg * BK]);
      gl2lds16(Bw + (size_t)(col0 + rg + srow) * K + k0 + scol, &Bs[rg * BK]);
    }
    __syncthreads();
    bf16x8 af[4], bf[4];
#pragma unroll
    for (int i = 0; i < 4; ++i) {
      af[i] = *reinterpret_cast<const bf16x8*>(&As[(wm + i * 16 + fr) * BK + fk]);
      bf[i] = *reinterpret_cast<const bf16x8*>(&Bs[(wn + i * 16 + fr) * BK + fk]);
    }
#pragma unroll
    for (int i = 0; i < 4; ++i)
#pragma unroll
      for (int j = 0; j < 4; ++j)
        acc[i][j] = __builtin_amdgcn_mfma_f32_16x16x32_bf16(af[i], bf[j], acc[i][j], 0, 0, 0);
    __syncthreads();
  }

#pragma unroll
  for (int j = 0; j < 4; ++j) {
    int col = col0 + wn + j * 16 + fr;
    float bv = bias[col];
#pragma unroll
    for (int i = 0; i < 4; ++i) {
      int rowb = row0 + wm + i * 16 + (lane >> 4) * 4;
#pragma unroll
      for (int r = 0; r < 4; ++r)
        Cout[(size_t)(rowb + r) * N + col] = acc[i][j][r] + bv;
    }
  }
}

// ---------------- attention: LDS-staged tiles + wave-owns-keys (r7, VALU diet) ----
__global__ __launch_bounds__(256, 2)
void attn_kernel(const u16* __restrict__ Q, const u16* __restrict__ Kmat,
                 const u16* __restrict__ VT, u16* __restrict__ O) {
  constexpr int LDK = 72, LDV = 72;
  // union: loop phase Ks(9216)+Vs(9216) == epilogue Of(17408)+Qs(1024)
  __shared__ alignas(16) unsigned char smem[18432];
  u16* Ks = (u16*)smem;                       // [key][d]
  u16* Vs = (u16*)(smem + 9216);              // [d][key]
  float* Of = (float*)smem;                   // [q][68]
  float* Qs = (float*)(smem + 17408);         // [wave][64]
  const int tid = threadIdx.x, wave = tid >> 6, lane = tid & 63;
  const int bh = blockIdx.x, qt = blockIdx.y;
  const int b = bh >> 4, h = bh & 15;
  const size_t base = (size_t)b * Tt * Cc + (size_t)h * Dd;
  const int fr = lane & 15, qd = lane >> 4;

  // Q fragments for all 4 q-blocks (B-operand: B[k=qd*8+j][n=fr])
  bf16x8 bq0[4], bq1[4];
#pragma unroll
  for (int nb = 0; nb < 4; ++nb) {
    const u16* qp = Q + base + (size_t)(qt * 64 + nb * 16 + fr) * Cc + qd * 8;
    bq0[nb] = *reinterpret_cast<const bf16x8*>(qp);
    bq1[nb] = *reinterpret_cast<const bf16x8*>(qp + 32);
  }

  f32x4 Oacc[4][4] = {};     // [n=dblock][nb=qblock]; O^T[d=n*16+qd*4+r][q=nb*16+fr]
  f32x2 sacc2[4] = {};       // packed per-q partial sums (v_pk_add_f32)
  const size_t vtb = (size_t)bh * Dd * Tt;
  const int sr = tid >> 3, sc = (tid & 7) * 8;

  for (int kt = 0; kt < Tt; kt += 64) {
#pragma unroll
    for (int it = 0; it < 2; ++it) {
      int r = it * 32 + sr;
      *reinterpret_cast<uint4*>(&Ks[r * LDK + sc]) =
          *reinterpret_cast<const uint4*>(Kmat + base + (size_t)(kt + r) * Cc + sc);
      *reinterpret_cast<uint4*>(&Vs[r * LDV + sc]) =
          *reinterpret_cast<const uint4*>(VT + vtb + (size_t)r * Tt + kt + sc);
    }
    __syncthreads();

    bf16x8 ka = *reinterpret_cast<const bf16x8*>(&Ks[(wave * 16 + fr) * LDK + qd * 8]);
    bf16x8 kb = *reinterpret_cast<const bf16x8*>(&Ks[(wave * 16 + fr) * LDK + 32 + qd * 8]);
    s16x4 va[4];
#pragma unroll
    for (int n = 0; n < 4; ++n)
      va[n] = *reinterpret_cast<const s16x4*>(&Vs[(n * 16 + fr) * LDV + wave * 16 + qd * 4]);

    s16x4 pf[4];
#pragma unroll
    for (int nb = 0; nb < 4; ++nb) {
      f32x4 z = {};
      z = __builtin_amdgcn_mfma_f32_16x16x32_bf16(ka, bq0[nb], z, 0, 0, 0);
      f32x4 st = __builtin_amdgcn_mfma_f32_16x16x32_bf16(kb, bq1[nb], z, 0, 0, 0);
      float p0 = EXP2F(st[0]), p1 = EXP2F(st[1]);
      float p2 = EXP2F(st[2]), p3 = EXP2F(st[3]);
      sacc2[nb] += (f32x2){p0, p1} + (f32x2){p2, p3};
      union { __hip_bfloat162 h2; short2 s2; } u01, u23;
      u01.h2 = __float22bfloat162_rn(make_float2(p0, p1));
      u23.h2 = __float22bfloat162_rn(make_float2(p2, p3));
      s16x4 pv; pv[0] = u01.s2.x; pv[1] = u01.s2.y;
      pv[2] = u23.s2.x; pv[3] = u23.s2.y;
      pf[nb] = pv;
    }

#pragma unroll
    for (int n = 0; n < 4; ++n)
#pragma unroll
      for (int nb = 0; nb < 4; ++nb)
        Oacc[n][nb] = MFMA_16x16x16_BF16(va[n], pf[nb], Oacc[n][nb]);

    __syncthreads();
  }

  // ---- epilogue: reduce q-sums and partial O^T across the 4 waves ----
#pragma unroll
  for (int nb = 0; nb < 4; ++nb) {
    float s = sacc2[nb][0] + sacc2[nb][1];
    s += __shfl_xor(s, 16, 64);
    s += __shfl_xor(s, 32, 64);
    if (qd == 0) Qs[wave * 64 + nb * 16 + fr] = s;
  }
  for (int w = 0; w < 4; ++w) {
    if (wave == w) {
#pragma unroll
      for (int n = 0; n < 4; ++n)
#pragma unroll
        for (int nb = 0; nb < 4; ++nb) {
          float* dst = &Of[(nb * 16 + fr) * 68 + n * 16 + qd * 4];
          if (w == 0) *reinterpret_cast<f32x4*>(dst) = Oacc[n][nb];
          else {
            f32x4 old = *reinterpret_cast<const f32x4*>(dst);
            *reinterpret_cast<f32x4*>(dst) = old + Oacc[n][nb];
          }
        }
    }
    __syncthreads();
  }

  {
    int q = tid >> 2, dg = tid & 3;
    float qtot = Qs[q] + Qs[64 + q] + Qs[128 + q] + Qs[192 + q];
    float linv = 1.0f / qtot;
    const float* src = &Of[q * 68 + dg * 16];
    alignas(16) u16 tmp[16];
#pragma unroll
    for (int i = 0; i < 16; ++i) tmp[i] = f32_to_bf16(src[i] * linv);
    u16* op = O + base + (size_t)(qt * 64 + q) * Cc + dg * 16;
    *reinterpret_cast<uint4*>(op)     = *reinterpret_cast<const uint4*>(tmp);
    *reinterpret_cast<uint4*>(op + 8) = *reinterpret_cast<const uint4*>(tmp + 8);
  }
}

extern "C" void kernel_launch(void* const* d_in, const int* in_sizes, int n_in,
                              void* d_out, int out_size, void* d_ws, size_t ws_size,
                              hipStream_t stream) {
  const float* x  = (const float*)d_in[0];
  const float* Wq = (const float*)d_in[1];
  const float* bq = (const float*)d_in[2];
  const float* Wk = (const float*)d_in[3];
  const float* bk = (const float*)d_in[4];
  const float* Wv = (const float*)d_in[5];
  const float* bv = (const float*)d_in[6];
  const float* Wo = (const float*)d_in[7];
  const float* bo = (const float*)d_in[8];

  const size_t NX = (size_t)Bb * Tt * Cc;  // 8388608
  const size_t NW = (size_t)Cc * Cc;       // 1048576

  u16* ws  = (u16*)d_ws;
  u16* xb  = ws;
  u16* wqb = ws + NX;     // wq|wk|wv contiguous -> the fused [3072,1024] B matrix
  u16* wkb = wqb + NW;
  u16* wvb = wkb + NW;
  u16* wob = wvb + NW;
  u16* qb  = wob + NW;
  u16* kb  = qb + NX;
  u16* vtb = kb + NX;
  u16* attnb = xb;  // alias: x dead once projections are done

  cast_f32_to_bf16<<<(int)(NX / 4 / 256), 256, 0, stream>>>(x, xb, (int)NX);
  cast4_f32_to_bf16<<<dim3((unsigned)(NW / 4 / 256), 4), 256, 0, stream>>>(
      Wq, Wk, Wv, Wo, wqb, wkb, wvb, wob, (int)NW);

  const float QSCL = 0.125f * 1.44269504f;  // 1/sqrt(D) * log2(e), folded into Q
  gemm_qkv<<<dim3(64, 24), 256, 0, stream>>>(xb, wqb, bq, bk, bv, qb, kb, vtb, QSCL);

  attn_kernel<<<dim3(Bb * Hh, Tt / 64), 256, 0, stream>>>(qb, kb, vtb, attnb);

  gemm_out<<<dim3(64, 8), 256, 0, stream>>>(attnb, wob, bo, (float*)d_out,
                                            Bb * Tt, Cc, Cc);
}